// Round 11
// baseline (141.926 us; speedup 1.0000x reference)
//
#include <hip/hip_runtime.h>

#define CROP_S 14
#define NPIX   196                  // 14*14
#define NCH    256
#define CPB    16                   // channels per item
#define NGRP   (NCH / CPB)          // 16 items per proposal
#define PROWS  12
#define PCOLS  16
#define PSZ    (PROWS * PCOLS)      // 192 floats per channel
#define OUTV4  (CPB * NPIX / 4)     // 784 float4 per item
#define QPC    (NPIX / 4)           // 49 float4 per channel (exact)
#define ITEMS  8                    // consecutive items per block

typedef float v4f __attribute__((ext_vector_type(4)));

struct Ctx {                        // per-item, block-uniform + per-lane pixel state
    const float* fbase;             // level base + c0*HW + xlo4
    int   M, HW, ylo;
    float x0s, y0s, bw, bh;
    int   xlo4;
    float* op;                      // out + item*CPB*NPIX
};

__global__ __launch_bounds__(256, 8) void roi_crop_kernel(
    const float* __restrict__ f0, const float* __restrict__ f1,
    const float* __restrict__ f2, const float* __restrict__ f3,
    const float* __restrict__ proposals, float* __restrict__ out,
    int n_items)
{
    __shared__ float s_patch[CPB * PSZ];      // 12 KB
    __shared__ int   s_o00[NPIX];
    __shared__ float s_wx[NPIX], s_wy[NPIX];  // 2.35 KB

    const int tid  = threadIdx.x;
    const int base = blockIdx.x * ITEMS;

    auto make_ctx = [&](float px0, float py0, float px1, float py1,
                        int item, Ctx& ic) {
        const float size = sqrtf((px1 - px0) * (py1 - py0));
        int lvl = 0; float bd = fabsf(size - 8.f), d;
        d = fabsf(size - 16.f); if (d < bd) { bd = d; lvl = 1; }
        d = fabsf(size - 32.f); if (d < bd) { bd = d; lvl = 2; }
        d = fabsf(size - 64.f); if (d < bd) { bd = d; lvl = 3; }
        const float* f = (lvl==0)?f0:(lvl==1)?f1:(lvl==2)?f2:f3;
        const float inv = (lvl==0)?0.5f:(lvl==1)?0.25f:(lvl==2)?0.125f:0.0625f;
        const int M = 256 >> lvl;
        ic.M = M; ic.HW = M * M;
        ic.x0s = px0*inv; ic.y0s = py0*inv;
        ic.bw = ((px1 - px0)*inv) * (1.f/CROP_S);
        ic.bh = ((py1 - py0)*inv) * (1.f/CROP_S);
        ic.ylo = min(max((int)floorf(ic.y0s + 0.5f*ic.bh - 0.5f), 0), M-1);
        int xlo4 = (min(max((int)floorf(ic.x0s + 0.5f*ic.bw - 0.5f), 0), M-1)) & ~3;
        xlo4 = min(xlo4, M - PCOLS);
        ic.xlo4 = xlo4;
        const int n  = item >> 4;
        const int c0 = (item & 15) * CPB;
        ic.fbase = f + (size_t)c0 * ic.HW + xlo4;
        ic.op = out + (size_t)n * (NCH*NPIX) + (size_t)c0 * NPIX;
    };

    auto issue = [&](const Ctx& ic, v4f& v0, v4f& v1, v4f& v2) {
        const float* fb = ic.fbase;
        const int M = ic.M, HW = ic.HW, ylo = ic.ylo;
        {   const int c = tid / 48, rem = tid - c*48;
            const int gy = min(ylo + (rem>>2), M-1);
            v0 = *reinterpret_cast<const v4f*>(fb + (size_t)c*HW + gy*M + (rem&3)*4); }
        {   const int s = 256 + tid, c = s / 48, rem = s - c*48;
            const int gy = min(ylo + (rem>>2), M-1);
            v1 = *reinterpret_cast<const v4f*>(fb + (size_t)c*HW + gy*M + (rem&3)*4); }
        {   const int s = 512 + tid, c = s / 48, rem = s - c*48;
            const int gy = min(ylo + (rem>>2), M-1);
            v2 = *reinterpret_cast<const v4f*>(fb + (size_t)c*HW + gy*M + (rem&3)*4); }
    };

    auto stage_and_params = [&](const Ctx& ic, const v4f& v0, const v4f& v1, const v4f& v2) {
        *reinterpret_cast<v4f*>(&s_patch[tid*4])       = v0;
        *reinterpret_cast<v4f*>(&s_patch[(256+tid)*4]) = v1;
        *reinterpret_cast<v4f*>(&s_patch[(512+tid)*4]) = v2;
        if (tid < NPIX) {
            const int y = tid / CROP_S;
            const int x = tid - y * CROP_S;
            const float xs = ic.x0s + ((float)x + 0.5f)*ic.bw - 0.5f;
            const float ys = ic.y0s + ((float)y + 0.5f)*ic.bh - 0.5f;
            const float fx = floorf(xs), fy = floorf(ys);
            s_wx[tid] = xs - fx;               // frac BEFORE clip (matches ref)
            s_wy[tid] = ys - fy;
            const int xi0 = min(max((int)fx, 0), ic.M-1);
            const int yi0 = min(max((int)fy, 0), ic.M-1);
            const int ci0 = min(max(xi0 - ic.xlo4, 0), PCOLS-2);  // xi1==xi0+1 always
            const int ri0 = min(max(yi0 - ic.ylo,  0), PROWS-2);
            s_o00[tid] = ri0 * PCOLS + ci0;
        }
    };

    auto writeout = [&](const Ctx& ic) {
        v4f* ob = reinterpret_cast<v4f*>(ic.op);
        #pragma unroll
        for (int i = 0; i < 4; ++i) {
            const int idx4 = i * 256 + tid;    // [0,1024) vs 784
            if (idx4 < OUTV4) {
                const int c  = idx4 / QPC;
                const int p0 = (idx4 - c * QPC) * 4;
                const float* pp = s_patch + c * PSZ;
                v4f v;
                #pragma unroll
                for (int j = 0; j < 4; ++j) {
                    const int   p  = p0 + j;
                    const int   o  = s_o00[p];
                    const float wx = s_wx[p], wy = s_wy[p];
                    const float v00 = pp[o],         v01 = pp[o + 1];
                    const float v10 = pp[o + PCOLS], v11 = pp[o + PCOLS + 1];
                    const float r0 = v00 + wx*(v01 - v00);
                    const float r1 = v10 + wx*(v11 - v10);
                    v[j] = r0 + wy*(r1 - r0);
                }
                __builtin_nontemporal_store(v, ob + idx4);
            }
        }
    };

    Ctx ic[2];
    v4f sv[2][3];
    float pr[2][4];

    // ---- prologue: item 0 loads in flight; proposal for item 1 ----
    {   const int n0 = base >> 4;
        pr[0][0] = proposals[n0*7+1]; pr[0][1] = proposals[n0*7+2];
        pr[0][2] = proposals[n0*7+3]; pr[0][3] = proposals[n0*7+4]; }
    make_ctx(pr[0][0],pr[0][1],pr[0][2],pr[0][3], base, ic[0]);
    issue(ic[0], sv[0][0], sv[0][1], sv[0][2]);
    if (base + 1 < n_items) {
        const int n1 = (base + 1) >> 4;
        pr[1][0] = proposals[n1*7+1]; pr[1][1] = proposals[n1*7+2];
        pr[1][2] = proposals[n1*7+3]; pr[1][3] = proposals[n1*7+4];
    }

    #pragma unroll
    for (int k = 0; k < ITEMS; ++k) {
        const int cur = k & 1, nxt = cur ^ 1;
        if (base + k >= n_items) break;                    // block-uniform
        stage_and_params(ic[cur], sv[cur][0], sv[cur][1], sv[cur][2]);
        __syncthreads();                                   // staging visible
        if (k < ITEMS-1 && base + k + 1 < n_items) {
            make_ctx(pr[nxt][0],pr[nxt][1],pr[nxt][2],pr[nxt][3],
                     base + k + 1, ic[nxt]);
            issue(ic[nxt], sv[nxt][0], sv[nxt][1], sv[nxt][2]);  // hides under writeout
            if (k < ITEMS-2 && base + k + 2 < n_items) {
                const int n2 = (base + k + 2) >> 4;
                pr[cur][0] = proposals[n2*7+1]; pr[cur][1] = proposals[n2*7+2];
                pr[cur][2] = proposals[n2*7+3]; pr[cur][3] = proposals[n2*7+4];
            }
        }
        writeout(ic[cur]);
        __syncthreads();                                   // reads done before next stage
    }
}

extern "C" void kernel_launch(void* const* d_in, const int* in_sizes, int n_in,
                              void* d_out, int out_size, void* d_ws, size_t ws_size,
                              hipStream_t stream) {
    const float* f0 = (const float*)d_in[0];
    const float* f1 = (const float*)d_in[1];
    const float* f2 = (const float*)d_in[2];
    const float* f3 = (const float*)d_in[3];
    const float* proposals = (const float*)d_in[4];
    float* out = (float*)d_out;

    const int N = in_sizes[4] / 7;            // 1024 proposals
    const int n_items = N * NGRP;             // 16384
    const int grid = (n_items + ITEMS - 1) / ITEMS;  // 2048

    roi_crop_kernel<<<dim3(grid), dim3(256), 0, stream>>>(
        f0, f1, f2, f3, proposals, out, n_items);
}

// Round 12
// 80.945 us; speedup vs baseline: 1.7534x; 1.7534x over previous
//
#include <hip/hip_runtime.h>

#define CROP_S 14
#define NPIX   196                  // 14*14
#define NCH    256
#define CPB    16                   // channels per item
#define NGRP   (NCH / CPB)          // 16 items per proposal
#define PROWS  12
#define PCOLS  16
#define PSZ    (PROWS * PCOLS)      // 192 floats per channel
#define OUTV4  (CPB * NPIX / 4)     // 784 float4 per item
#define QPC    (NPIX / 4)           // 49 float4 per channel (exact)
#define ITEMS  8                    // consecutive items per block

typedef float v4f __attribute__((ext_vector_type(4)));

struct Ctx {                        // named-field struct: SROA-able, stays in regs
    const float* fbase;             // level base + c0*HW + xlo4
    float*       op;                // out + item*CPB*NPIX
    int   M, HW, ylo, xlo4;
    float x0s, y0s, bw, bh;
};

__global__ __launch_bounds__(256) void roi_crop_kernel(
    const float* __restrict__ f0, const float* __restrict__ f1,
    const float* __restrict__ f2, const float* __restrict__ f3,
    const float* __restrict__ proposals, float* __restrict__ out,
    int n_items)
{
    __shared__ float s_patchA[CPB * PSZ];     // 12 KB
    __shared__ float s_patchB[CPB * PSZ];     // 12 KB
    __shared__ int   s_o00A[NPIX]; __shared__ int   s_o00B[NPIX];
    __shared__ float s_wxA[NPIX];  __shared__ float s_wxB[NPIX];
    __shared__ float s_wyA[NPIX];  __shared__ float s_wyB[NPIX];

    const int tid  = threadIdx.x;
    const int base = blockIdx.x * ITEMS;

    auto make_ctx = [&](float px0, float py0, float px1, float py1, int item) {
        Ctx ic;
        const float size = sqrtf((px1 - px0) * (py1 - py0));
        int lvl = 0; float bd = fabsf(size - 8.f), d;
        d = fabsf(size - 16.f); if (d < bd) { bd = d; lvl = 1; }
        d = fabsf(size - 32.f); if (d < bd) { bd = d; lvl = 2; }
        d = fabsf(size - 64.f); if (d < bd) { bd = d; lvl = 3; }
        const float* f = (lvl==0)?f0:(lvl==1)?f1:(lvl==2)?f2:f3;
        const float inv = (lvl==0)?0.5f:(lvl==1)?0.25f:(lvl==2)?0.125f:0.0625f;
        const int M = 256 >> lvl;
        ic.M = M; ic.HW = M * M;
        ic.x0s = px0*inv; ic.y0s = py0*inv;
        ic.bw = ((px1 - px0)*inv) * (1.f/CROP_S);
        ic.bh = ((py1 - py0)*inv) * (1.f/CROP_S);
        ic.ylo = min(max((int)floorf(ic.y0s + 0.5f*ic.bh - 0.5f), 0), M-1);
        int xlo4 = (min(max((int)floorf(ic.x0s + 0.5f*ic.bw - 0.5f), 0), M-1)) & ~3;
        ic.xlo4 = min(xlo4, M - PCOLS);
        const int n  = item >> 4;
        const int c0 = (item & 15) * CPB;
        ic.fbase = f + (size_t)c0 * ic.HW + ic.xlo4;
        ic.op = out + (size_t)n * (NCH*NPIX) + (size_t)c0 * NPIX;
        return ic;
    };

    // async DMA: 3 x global_load_lds(16B). LDS dest is wave-uniform base +
    // lane*16, which matches s_patch[sidx*4] with sidx = it*256 + tid exactly.
    auto issue = [&](const Ctx& ic, float* lbuf) {
        const float* fb = ic.fbase;
        const int M = ic.M, HW = ic.HW, ylo = ic.ylo;
        #pragma unroll
        for (int it = 0; it < 3; ++it) {
            const int sidx = it * 256 + tid;
            const int c = sidx / 48, rem = sidx - c * 48;
            const int gy = min(ylo + (rem >> 2), M - 1);
            const float* g = fb + (size_t)c * HW + gy * M + (rem & 3) * 4;
            __builtin_amdgcn_global_load_lds(
                (const __attribute__((address_space(1))) void*)g,
                (__attribute__((address_space(3))) void*)(lbuf + sidx * 4),
                16, 0, 0);
        }
    };

    auto params = [&](const Ctx& ic, int* o00, float* wxb, float* wyb) {
        if (tid < NPIX) {
            const int y = tid / CROP_S;
            const int x = tid - y * CROP_S;
            const float xs = ic.x0s + ((float)x + 0.5f)*ic.bw - 0.5f;
            const float ys = ic.y0s + ((float)y + 0.5f)*ic.bh - 0.5f;
            const float fx = floorf(xs), fy = floorf(ys);
            wxb[tid] = xs - fx;               // frac BEFORE clip (matches ref)
            wyb[tid] = ys - fy;
            const int xi0 = min(max((int)fx, 0), ic.M-1);
            const int yi0 = min(max((int)fy, 0), ic.M-1);
            const int ci0 = min(max(xi0 - ic.xlo4, 0), PCOLS-2);  // xi1==xi0+1 always
            const int ri0 = min(max(yi0 - ic.ylo,  0), PROWS-2);
            o00[tid] = ri0 * PCOLS + ci0;
        }
    };

    auto writeout = [&](const Ctx& ic, const float* lbuf,
                        const int* o00, const float* wxb, const float* wyb) {
        v4f* ob = reinterpret_cast<v4f*>(ic.op);
        #pragma unroll
        for (int i = 0; i < 4; ++i) {
            const int idx4 = i * 256 + tid;   // [0,1024) vs 784
            if (idx4 < OUTV4) {
                const int c  = idx4 / QPC;
                const int p0 = (idx4 - c * QPC) * 4;
                const float* pp = lbuf + c * PSZ;
                v4f v;
                #pragma unroll
                for (int j = 0; j < 4; ++j) {
                    const int   p  = p0 + j;
                    const int   o  = o00[p];
                    const float wx = wxb[p], wy = wyb[p];
                    const float v00 = pp[o],         v01 = pp[o + 1];
                    const float v10 = pp[o + PCOLS], v11 = pp[o + PCOLS + 1];
                    const float r0 = v00 + wx*(v01 - v00);
                    const float r1 = v10 + wx*(v11 - v10);
                    v[j] = r0 + wy*(r1 - r0);
                }
                __builtin_nontemporal_store(v, ob + idx4);
            }
        }
    };

    // ---- prologue ----
    float a0, a1, a2, a3, b0, b1, b2, b3;
    {   const int n0 = base >> 4;
        a0 = proposals[n0*7+1]; a1 = proposals[n0*7+2];
        a2 = proposals[n0*7+3]; a3 = proposals[n0*7+4]; }
    Ctx cA = make_ctx(a0, a1, a2, a3, base);
    issue(cA, s_patchA);                      // item 0 DMA in flight
    {   const int n1 = (base + 1) >> 4;
        b0 = proposals[n1*7+1]; b1 = proposals[n1*7+2];
        b2 = proposals[n1*7+3]; b3 = proposals[n1*7+4]; }
    Ctx cB;

    #pragma unroll
    for (int k = 0; k < ITEMS; k += 2) {
        // ---- phase A: item base+k (buf A) ----
        params(cA, s_o00A, s_wxA, s_wyA);
        cB = make_ctx(b0, b1, b2, b3, base + k + 1);
        __syncthreads();                      // drains bufA DMA; prev writeoutB done
        issue(cB, s_patchB);                  // item k+1 DMA flies under writeoutA
        if (k + 2 < ITEMS) {
            const int n2 = (base + k + 2) >> 4;
            a0 = proposals[n2*7+1]; a1 = proposals[n2*7+2];
            a2 = proposals[n2*7+3]; a3 = proposals[n2*7+4];
        }
        writeout(cA, s_patchA, s_o00A, s_wxA, s_wyA);

        // ---- phase B: item base+k+1 (buf B) ----
        params(cB, s_o00B, s_wxB, s_wyB);
        if (k + 2 < ITEMS) cA = make_ctx(a0, a1, a2, a3, base + k + 2);
        __syncthreads();                      // drains bufB DMA; writeoutA done
        if (k + 2 < ITEMS) issue(cA, s_patchA);   // item k+2 DMA under writeoutB
        if (k + 3 < ITEMS) {
            const int n3 = (base + k + 3) >> 4;
            b0 = proposals[n3*7+1]; b1 = proposals[n3*7+2];
            b2 = proposals[n3*7+3]; b3 = proposals[n3*7+4];
        }
        writeout(cB, s_patchB, s_o00B, s_wxB, s_wyB);
    }
}

extern "C" void kernel_launch(void* const* d_in, const int* in_sizes, int n_in,
                              void* d_out, int out_size, void* d_ws, size_t ws_size,
                              hipStream_t stream) {
    const float* f0 = (const float*)d_in[0];
    const float* f1 = (const float*)d_in[1];
    const float* f2 = (const float*)d_in[2];
    const float* f3 = (const float*)d_in[3];
    const float* proposals = (const float*)d_in[4];
    float* out = (float*)d_out;

    const int N = in_sizes[4] / 7;            // 1024 proposals
    const int n_items = N * NGRP;             // 16384 (divisible by ITEMS)
    const int grid = n_items / ITEMS;         // 2048

    roi_crop_kernel<<<dim3(grid), dim3(256), 0, stream>>>(
        f0, f1, f2, f3, proposals, out, n_items);
}

// Round 13
// 67.898 us; speedup vs baseline: 2.0903x; 1.1922x over previous
//
#include <hip/hip_runtime.h>

#define CROP_S 14
#define NPIX   196                  // 14*14
#define NCH    256
#define CPB    16                   // channels per block
#define NGRP   (NCH / CPB)          // 16 blocks per proposal
#define PROWS  12                   // patch rows (span provably <= 12)
#define PCOLS  16                   // patch cols (span<=11 + <=3 align slack, float4-aligned)
#define PSZ    (PROWS * PCOLS)      // 192 floats per channel
#define STAGE_V4 (CPB * PSZ / 4)    // 768 float4 loads -> 3 per thread
#define OUTV4  (CPB * NPIX / 4)     // 784 float4 per item
#define QPC    (NPIX / 4)           // 49 float4 per channel (exact)

typedef float v4f __attribute__((ext_vector_type(4)));

__global__ __launch_bounds__(256) void roi_crop_kernel(
    const float* __restrict__ f0, const float* __restrict__ f1,
    const float* __restrict__ f2, const float* __restrict__ f3,
    const float* __restrict__ proposals, float* __restrict__ out)
{
    __shared__ float s_patch[CPB * PSZ];      // 12 KB: [c][12][16]
    __shared__ int   s_o00[NPIX];             // per-pixel corner base
    __shared__ float s_wx[NPIX], s_wy[NPIX];  // per-pixel fracs

    const int bid = blockIdx.x;
    const int n   = bid >> 4;          // proposal
    const int cg  = bid & (NGRP - 1);  // channel group
    const int c0  = cg * CPB;
    const int tid = threadIdx.x;

    // ---- per-proposal box / level (uniform across block; L2-hit loads) ----
    const float px0 = proposals[n * 7 + 1];
    const float py0 = proposals[n * 7 + 2];
    const float px1 = proposals[n * 7 + 3];
    const float py1 = proposals[n * 7 + 4];

    const float size = sqrtf((px1 - px0) * (py1 - py0));
    int lvl = 0;
    float bd = fabsf(size - 8.0f);
    {
        float d1 = fabsf(size - 16.0f);
        if (d1 < bd) { bd = d1; lvl = 1; }
        float d2 = fabsf(size - 32.0f);
        if (d2 < bd) { bd = d2; lvl = 2; }
        float d3 = fabsf(size - 64.0f);
        if (d3 < bd) { bd = d3; lvl = 3; }
    }

    const float* f = (lvl == 0) ? f0 : (lvl == 1) ? f1 : (lvl == 2) ? f2 : f3;
    const float stride = (float)(2 << lvl);   // 2,4,8,16 (pow2 -> exact divide)
    const int   M      = 256 >> lvl;          // H == W
    const int   HW     = M * M;

    const float x0s = px0 / stride, y0s = py0 / stride;
    const float x1s = px1 / stride, y1s = py1 / stride;
    const float bw = (x1s - x0s) / (float)CROP_S;
    const float bh = (y1s - y0s) / (float)CROP_S;

    // patch origin: floor of minimal sample coord; x aligned down to float4
    const int ylo  = min(max((int)floorf(y0s + 0.5f * bh - 0.5f), 0), M - 1);
    int xlo4 = min(max((int)floorf(x0s + 0.5f * bw - 0.5f), 0), M - 1) & ~3;
    xlo4 = min(xlo4, M - PCOLS);              // vector loads stay inside tensor

    // ---- stage CPB channels x 12x16 patch via float4 (3 per thread) ----
    {
        const float* fbase = f + (size_t)c0 * HW + xlo4;
        #pragma unroll
        for (int it = 0; it < STAGE_V4 / 256; ++it) {
            const int sidx = it * 256 + tid;         // [0,768)
            const int c    = sidx / (PSZ / 4);       // /48
            const int rem  = sidx - c * (PSZ / 4);
            const int r    = rem >> 2;               // row 0..11
            const int q    = rem & 3;                // col quad
            const int gy   = min(ylo + r, M - 1);    // edge-replicate rows
            const v4f v = *reinterpret_cast<const v4f*>(
                fbase + (size_t)c * HW + gy * M + q * 4);
            *reinterpret_cast<v4f*>(&s_patch[sidx * 4]) = v;
        }
    }

    // ---- per-pixel bilinear params into LDS (same phase as staging) ----
    if (tid < NPIX) {
        const int y = tid / CROP_S;
        const int x = tid - y * CROP_S;
        const float xs = x0s + ((float)x + 0.5f) * bw - 0.5f;
        const float ys = y0s + ((float)y + 0.5f) * bh - 0.5f;
        const float fx = floorf(xs), fy = floorf(ys);
        // frac BEFORE clip (matches reference)
        s_wx[tid] = xs - fx;
        s_wy[tid] = ys - fy;
        // Upper clamp provably never binds: xi1 == xi0+1, yi1 == yi0+1 always.
        const int xi0 = min(max((int)fx, 0), M - 1);
        const int yi0 = min(max((int)fy, 0), M - 1);
        const int ci0 = min(xi0 - xlo4, PCOLS - 2);
        const int ri0 = min(yi0 - ylo,  PROWS - 2);
        s_o00[tid] = ri0 * PCOLS + ci0;       // corners at +0, +1, +16, +17
    }
    __syncthreads();   // the ONLY barrier

    // ---- fused interp + full-line float4 writeout (plain stores: L2 buffers
    //      the burst and smooths the HBM write drain; NT gave no reservoir) ----
    v4f* ob = reinterpret_cast<v4f*>(
        out + (size_t)n * (NCH * NPIX) + (size_t)c0 * NPIX);  // 16B-aligned
    #pragma unroll
    for (int i = 0; i < 4; ++i) {
        const int idx4 = i * 256 + tid;       // [0,1024) vs OUTV4=784
        if (idx4 < OUTV4) {
            const int c  = idx4 / QPC;        // channel (float4 never crosses channels)
            const int pq = idx4 - c * QPC;
            const int p0 = pq * 4;            // 4 consecutive pixels
            const float* pp = s_patch + c * PSZ;
            v4f v;
            #pragma unroll
            for (int j = 0; j < 4; ++j) {
                const int   p  = p0 + j;
                const int   o  = s_o00[p];
                const float wx = s_wx[p];
                const float wy = s_wy[p];
                const float v00 = pp[o],         v01 = pp[o + 1];
                const float v10 = pp[o + PCOLS], v11 = pp[o + PCOLS + 1];
                const float r0 = v00 + wx * (v01 - v00);
                const float r1 = v10 + wx * (v11 - v10);
                v[j] = r0 + wy * (r1 - r0);
            }
            ob[idx4] = v;                     // plain full-line store
        }
    }
}

extern "C" void kernel_launch(void* const* d_in, const int* in_sizes, int n_in,
                              void* d_out, int out_size, void* d_ws, size_t ws_size,
                              hipStream_t stream) {
    const float* f0 = (const float*)d_in[0];
    const float* f1 = (const float*)d_in[1];
    const float* f2 = (const float*)d_in[2];
    const float* f3 = (const float*)d_in[3];
    const float* proposals = (const float*)d_in[4];
    float* out = (float*)d_out;

    const int N = in_sizes[4] / 7;   // 1024 proposals

    roi_crop_kernel<<<dim3(N * NGRP), dim3(256), 0, stream>>>(f0, f1, f2, f3, proposals, out);
}

// Round 14
// 56.542 us; speedup vs baseline: 2.5101x; 1.2008x over previous
//
#include <hip/hip_runtime.h>

#define CROP_S 14
#define NPIX   196                  // 14*14
#define NCH    256
#define CPB    32                   // channels per block (doubled vs R10)
#define NGRP   (NCH / CPB)          // 8 blocks per proposal
#define NTHR   512                  // 8 waves per block
#define PROWS  12                   // patch rows (span provably <= 12)
#define PCOLS  16                   // patch cols (span<=11 + <=3 align slack, float4-aligned)
#define PSZ    (PROWS * PCOLS)      // 192 floats per channel
#define STAGE_V4 (CPB * PSZ / 4)    // 1536 float4 loads -> 3 per thread
#define OUTV4  (CPB * NPIX / 4)     // 1568 float4 per block
#define QPC    (NPIX / 4)           // 49 float4 per channel (exact)

typedef float v4f __attribute__((ext_vector_type(4)));

__global__ __launch_bounds__(NTHR) void roi_crop_kernel(
    const float* __restrict__ f0, const float* __restrict__ f1,
    const float* __restrict__ f2, const float* __restrict__ f3,
    const float* __restrict__ proposals, float* __restrict__ out)
{
    __shared__ float s_patch[CPB * PSZ];      // 24 KB: [c][12][16]
    __shared__ int   s_o00[NPIX];             // per-pixel corner base
    __shared__ float s_wx[NPIX], s_wy[NPIX];  // per-pixel fracs

    const int bid = blockIdx.x;
    const int n   = bid >> 3;          // proposal
    const int cg  = bid & (NGRP - 1);  // channel group
    const int c0  = cg * CPB;
    const int tid = threadIdx.x;

    // ---- per-proposal box / level (uniform across block; L2-hit loads) ----
    const float px0 = proposals[n * 7 + 1];
    const float py0 = proposals[n * 7 + 2];
    const float px1 = proposals[n * 7 + 3];
    const float py1 = proposals[n * 7 + 4];

    const float size = sqrtf((px1 - px0) * (py1 - py0));
    int lvl = 0;
    float bd = fabsf(size - 8.0f);
    {
        float d1 = fabsf(size - 16.0f);
        if (d1 < bd) { bd = d1; lvl = 1; }
        float d2 = fabsf(size - 32.0f);
        if (d2 < bd) { bd = d2; lvl = 2; }
        float d3 = fabsf(size - 64.0f);
        if (d3 < bd) { bd = d3; lvl = 3; }
    }

    const float* f = (lvl == 0) ? f0 : (lvl == 1) ? f1 : (lvl == 2) ? f2 : f3;
    const float stride = (float)(2 << lvl);   // 2,4,8,16 (pow2 -> exact divide)
    const int   M      = 256 >> lvl;          // H == W
    const int   HW     = M * M;

    const float x0s = px0 / stride, y0s = py0 / stride;
    const float x1s = px1 / stride, y1s = py1 / stride;
    const float bw = (x1s - x0s) / (float)CROP_S;
    const float bh = (y1s - y0s) / (float)CROP_S;

    // patch origin: floor of minimal sample coord; x aligned down to float4
    const int ylo  = min(max((int)floorf(y0s + 0.5f * bh - 0.5f), 0), M - 1);
    int xlo4 = min(max((int)floorf(x0s + 0.5f * bw - 0.5f), 0), M - 1) & ~3;
    xlo4 = min(xlo4, M - PCOLS);              // vector loads stay inside tensor

    // ---- stage CPB channels x 12x16 patch via float4 (3 per thread) ----
    {
        const float* fbase = f + (size_t)c0 * HW + xlo4;
        #pragma unroll
        for (int it = 0; it < STAGE_V4 / NTHR; ++it) {
            const int sidx = it * NTHR + tid;        // [0,1536)
            const int c    = sidx / (PSZ / 4);       // /48
            const int rem  = sidx - c * (PSZ / 4);
            const int r    = rem >> 2;               // row 0..11
            const int q    = rem & 3;                // col quad
            const int gy   = min(ylo + r, M - 1);    // edge-replicate rows
            const v4f v = *reinterpret_cast<const v4f*>(
                fbase + (size_t)c * HW + gy * M + q * 4);
            *reinterpret_cast<v4f*>(&s_patch[sidx * 4]) = v;
        }
    }

    // ---- per-pixel bilinear params into LDS (same phase as staging) ----
    if (tid < NPIX) {
        const int y = tid / CROP_S;
        const int x = tid - y * CROP_S;
        const float xs = x0s + ((float)x + 0.5f) * bw - 0.5f;
        const float ys = y0s + ((float)y + 0.5f) * bh - 0.5f;
        const float fx = floorf(xs), fy = floorf(ys);
        // frac BEFORE clip (matches reference)
        s_wx[tid] = xs - fx;
        s_wy[tid] = ys - fy;
        // Upper clamp provably never binds: xi1 == xi0+1, yi1 == yi0+1 always.
        const int xi0 = min(max((int)fx, 0), M - 1);
        const int yi0 = min(max((int)fy, 0), M - 1);
        const int ci0 = min(xi0 - xlo4, PCOLS - 2);
        const int ri0 = min(yi0 - ylo,  PROWS - 2);
        s_o00[tid] = ri0 * PCOLS + ci0;       // corners at +0, +1, +16, +17
    }
    __syncthreads();   // the ONLY barrier

    // ---- fused interp + full-line float4 NT writeout (all lanes) ----
    v4f* ob = reinterpret_cast<v4f*>(
        out + (size_t)n * (NCH * NPIX) + (size_t)c0 * NPIX);  // 16B-aligned
    #pragma unroll
    for (int i = 0; i < 4; ++i) {
        const int idx4 = i * NTHR + tid;      // [0,2048) vs OUTV4=1568
        if (idx4 < OUTV4) {
            const int c  = idx4 / QPC;        // channel (float4 never crosses channels)
            const int pq = idx4 - c * QPC;
            const int p0 = pq * 4;            // 4 consecutive pixels
            const float* pp = s_patch + c * PSZ;
            v4f v;
            #pragma unroll
            for (int j = 0; j < 4; ++j) {
                const int   p  = p0 + j;
                const int   o  = s_o00[p];
                const float wx = s_wx[p];
                const float wy = s_wy[p];
                const float v00 = pp[o],         v01 = pp[o + 1];
                const float v10 = pp[o + PCOLS], v11 = pp[o + PCOLS + 1];
                const float r0 = v00 + wx * (v01 - v00);
                const float r1 = v10 + wx * (v11 - v10);
                v[j] = r0 + wy * (r1 - r0);
            }
            __builtin_nontemporal_store(v, ob + idx4);
        }
    }
}

extern "C" void kernel_launch(void* const* d_in, const int* in_sizes, int n_in,
                              void* d_out, int out_size, void* d_ws, size_t ws_size,
                              hipStream_t stream) {
    const float* f0 = (const float*)d_in[0];
    const float* f1 = (const float*)d_in[1];
    const float* f2 = (const float*)d_in[2];
    const float* f3 = (const float*)d_in[3];
    const float* proposals = (const float*)d_in[4];
    float* out = (float*)d_out;

    const int N = in_sizes[4] / 7;   // 1024 proposals

    roi_crop_kernel<<<dim3(N * NGRP), dim3(NTHR), 0, stream>>>(f0, f1, f2, f3, proposals, out);
}